// Round 1
// baseline (354.124 us; speedup 1.0000x reference)
//
#include <hip/hip_runtime.h>

#define DIN 96
#define DP 48
#define NPOS (48*48*48)   // 110592
#define NG 1728           // 12^3
#define WIN3 343
#define NCH 64
#define NC2 32

// ---------------------------------------------------------------------------
// Kernel 1: fused depthwise conv (3x3x3, stride 2, pad 1) + bias
//           + pointwise (64->32) + bias + ReLU
//           + V projection (32->64)  -> V[pos][64]  (position-major)
//           + K score (row 0 of each head) * 1/sqrt(32) -> Ksc[2][NPOS]
// one thread per output voxel (48^3 = 110592 threads)
// ---------------------------------------------------------------------------
__global__ __launch_bounds__(256) void fused_front(
    const float* __restrict__ feat,   // [64][96][96][96]
    const float* __restrict__ dw_w,   // [64][27]
    const float* __restrict__ dw_b,   // [64]
    const float* __restrict__ pw_w,   // [32][64]
    const float* __restrict__ pw_b,   // [32]
    const float* __restrict__ k_w,    // [64][32]
    const float* __restrict__ v_w,    // [64][32]
    float* __restrict__ V,            // [NPOS][64]
    float* __restrict__ Ksc)          // [2][NPOS]
{
    const int pos = blockIdx.x * 256 + threadIdx.x;
    const int ow = pos % DP;
    const int oh = (pos / DP) % DP;
    const int od = pos / (DP * DP);

    float f2[NC2];
    #pragma unroll
    for (int o = 0; o < NC2; ++o) f2[o] = pw_b[o];

    #pragma unroll 1
    for (int c = 0; c < NCH; ++c) {
        float acc = dw_b[c];
        const float* fc = feat + (size_t)c * (DIN * DIN * DIN);
        const float* wc = dw_w + c * 27;
        #pragma unroll
        for (int kd = 0; kd < 3; ++kd) {
            int id = od * 2 - 1 + kd;
            if ((unsigned)id < (unsigned)DIN) {
                #pragma unroll
                for (int kh = 0; kh < 3; ++kh) {
                    int ih = oh * 2 - 1 + kh;
                    if ((unsigned)ih < (unsigned)DIN) {
                        const float* row = fc + ((size_t)id * DIN + ih) * DIN;
                        #pragma unroll
                        for (int kw = 0; kw < 3; ++kw) {
                            int iw = ow * 2 - 1 + kw;
                            if ((unsigned)iw < (unsigned)DIN)
                                acc = fmaf(row[iw], wc[(kd * 3 + kh) * 3 + kw], acc);
                        }
                    }
                }
            }
        }
        #pragma unroll
        for (int o = 0; o < NC2; ++o)
            f2[o] = fmaf(pw_w[o * NCH + c], acc, f2[o]);
    }

    #pragma unroll
    for (int o = 0; o < NC2; ++o) f2[o] = fmaxf(f2[o], 0.0f);

    // V projection, position-major write
    float* vout = V + (size_t)pos * NCH;
    #pragma unroll 1
    for (int j = 0; j < NCH; ++j) {
        float a = 0.0f;
        #pragma unroll
        for (int o = 0; o < NC2; ++o) a = fmaf(v_w[j * NC2 + o], f2[o], a);
        vout[j] = a;
    }

    // K score: rows 0 and 32 of k_w, pre-scaled by 1/sqrt(32)
    const float scale = 0.17677669529663687f;
    #pragma unroll
    for (int h = 0; h < 2; ++h) {
        float a = 0.0f;
        #pragma unroll
        for (int o = 0; o < NC2; ++o) a = fmaf(k_w[(h * 32) * NC2 + o], f2[o], a);
        Ksc[h * NPOS + pos] = a * scale;
    }
}

// ---------------------------------------------------------------------------
// Kernel 2: per-center windowed attention + output head
// one block (256 threads / 4 waves) per center g
// ---------------------------------------------------------------------------
__global__ __launch_bounds__(256) void attn_out(
    const float* __restrict__ V,      // [NPOS][64]
    const float* __restrict__ Ksc,    // [2][NPOS]
    const float* __restrict__ out_w,  // [3][64]
    const float* __restrict__ out_b,  // [3]
    float* __restrict__ out)          // [3][NG]
{
    // exact replication of numpy linspace + int() truncation (baked)
    const int lo_t[12] = {0,1,5,9,14,18,22,26,31,35,39,44};
    const int hi_t[12] = {4,8,12,16,21,25,29,33,38,42,46,48};

    const int g   = blockIdx.x;
    const int tid = threadIdx.x;
    const int lane = tid & 63;
    const int wv   = tid >> 6;

    const int gz = g % 12, gy = (g / 12) % 12, gx = g / 144;
    const int lox = lo_t[gx], hix = hi_t[gx];
    const int loy = lo_t[gy], hiy = hi_t[gy];
    const int loz = lo_t[gz], hiz = hi_t[gz];

    __shared__ int   s_flat[WIN3];        // bit31 set => masked out
    __shared__ float s_attn[2][WIN3];
    __shared__ float s_red[4];

    for (int w = tid; w < WIN3; w += 256) {
        int kd = w / 49, kh = (w / 7) % 7, kw = w % 7;
        int ix = lox + kd, iy = loy + kh, iz = loz + kw;
        bool m = (ix < hix) && (iy < hiy) && (iz < hiz);
        if (ix >= hix) ix = lox;
        if (iy >= hiy) iy = loy;
        if (iz >= hiz) iz = loz;
        int flat = (ix * DP + iy) * DP + iz;
        s_flat[w] = m ? flat : (flat | (int)0x80000000);
    }
    __syncthreads();

    const float NEG_INF = -__builtin_inff();
    float sums[2];

    #pragma unroll
    for (int h = 0; h < 2; ++h) {
        float sc0 = NEG_INF, sc1 = NEG_INF;
        {
            int w = tid;
            int fv = s_flat[w];
            if (fv >= 0) sc0 = Ksc[h * NPOS + fv];
        }
        if (tid + 256 < WIN3) {
            int fv = s_flat[tid + 256];
            if (fv >= 0) sc1 = Ksc[h * NPOS + fv];
        }
        float lmax = fmaxf(sc0, sc1);
        #pragma unroll
        for (int off = 32; off; off >>= 1) lmax = fmaxf(lmax, __shfl_xor(lmax, off));
        if (lane == 0) s_red[wv] = lmax;
        __syncthreads();
        float gmax = fmaxf(fmaxf(s_red[0], s_red[1]), fmaxf(s_red[2], s_red[3]));
        __syncthreads();   // protect s_red before reuse

        float lsum = 0.0f;
        {
            float e = (sc0 == NEG_INF) ? 0.0f : expf(sc0 - gmax);
            s_attn[h][tid] = e;
            lsum += e;
        }
        if (tid + 256 < WIN3) {
            float e = (sc1 == NEG_INF) ? 0.0f : expf(sc1 - gmax);
            s_attn[h][tid + 256] = e;
            lsum += e;
        }
        #pragma unroll
        for (int off = 32; off; off >>= 1) lsum += __shfl_xor(lsum, off);
        if (lane == 0) s_red[wv] = lsum;
        __syncthreads();
        sums[h] = s_red[0] + s_red[1] + s_red[2] + s_red[3];
        __syncthreads();   // protect s_red for next head
    }

    // PV: lane j = h*32+c ; each wave covers a strided subset of the window
    const int h = lane >> 5;
    float acc = 0.0f;
    for (int w = wv; w < WIN3; w += 4) {
        int fv = s_flat[w] & 0x7fffffff;
        float a = s_attn[h][w];
        acc = fmaf(a, V[(size_t)fv * NCH + lane], acc);
    }

    __shared__ float s_pctx[4][NCH];
    __shared__ float s_ctx[NCH];
    s_pctx[wv][lane] = acc;
    __syncthreads();
    if (wv == 0) {
        float ctx = s_pctx[0][lane] + s_pctx[1][lane] + s_pctx[2][lane] + s_pctx[3][lane];
        ctx /= sums[h];
        s_ctx[lane] = ctx;
    }
    __syncthreads();

    if (tid < 3) {
        float a = out_b[tid];
        #pragma unroll
        for (int j = 0; j < NCH; ++j) a = fmaf(out_w[tid * NCH + j], s_ctx[j], a);
        out[tid * NG + g] = a;
    }
}

// ---------------------------------------------------------------------------
extern "C" void kernel_launch(void* const* d_in, const int* in_sizes, int n_in,
                              void* d_out, int out_size, void* d_ws, size_t ws_size,
                              hipStream_t stream) {
    const float* feat  = (const float*)d_in[0];
    const float* dw_w  = (const float*)d_in[1];
    const float* dw_b  = (const float*)d_in[2];
    const float* pw_w  = (const float*)d_in[3];
    const float* pw_b  = (const float*)d_in[4];
    const float* k_w   = (const float*)d_in[5];
    const float* v_w   = (const float*)d_in[6];
    const float* out_w = (const float*)d_in[7];
    const float* out_b = (const float*)d_in[8];

    float* V   = (float*)d_ws;                      // NPOS*64 floats
    float* Ksc = V + (size_t)NPOS * NCH;            // 2*NPOS floats
    float* out = (float*)d_out;

    hipLaunchKernelGGL(fused_front, dim3(NPOS / 256), dim3(256), 0, stream,
                       feat, dw_w, dw_b, pw_w, pw_b, k_w, v_w, V, Ksc);
    hipLaunchKernelGGL(attn_out, dim3(NG), dim3(256), 0, stream,
                       V, Ksc, out_w, out_b, out);
}

// Round 2
// 218.025 us; speedup vs baseline: 1.6242x; 1.6242x over previous
//
#include <hip/hip_runtime.h>

#define DIN 96
#define DP 48
#define NPOS (48*48*48)   // 110592
#define NG 1728           // 12^3
#define WIN3 343
#define NCH 64
#define NC2 32

// ---------------------------------------------------------------------------
// Kernel A: depthwise 3x3x3 stride-2 pad-1 conv + bias -> dwout[c][pos]
// one thread per (channel, output voxel) : 64*110592 threads, 27648 blocks
// ---------------------------------------------------------------------------
__global__ __launch_bounds__(256) void dwconv(
    const float* __restrict__ feat,   // [64][96][96][96]
    const float* __restrict__ dw_w,   // [64][27]
    const float* __restrict__ dw_b,   // [64]
    float* __restrict__ dwout)        // [64][NPOS]
{
    const int blk_per_c = NPOS / 256;            // 432
    const int c   = blockIdx.x / blk_per_c;
    const int pos = (blockIdx.x % blk_per_c) * 256 + threadIdx.x;
    const int ow = pos % DP;
    const int oh = (pos / DP) % DP;
    const int od = pos / (DP * DP);

    const float* fc = feat + (size_t)c * (DIN * DIN * DIN);
    const float* wc = dw_w + c * 27;

    float acc = dw_b[c];
    // low edge is the only possible OOB (id = 2*od-1+kd >= -1; high side max 95)
    #pragma unroll
    for (int kd = 0; kd < 3; ++kd) {
        int id = od * 2 - 1 + kd;
        if (id >= 0) {
            #pragma unroll
            for (int kh = 0; kh < 3; ++kh) {
                int ih = oh * 2 - 1 + kh;
                if (ih >= 0) {
                    const float* row = fc + ((size_t)id * DIN + ih) * DIN + (ow * 2 - 1);
                    #pragma unroll
                    for (int kw = 0; kw < 3; ++kw) {
                        if (ow * 2 - 1 + kw >= 0)
                            acc = fmaf(row[kw], wc[(kd * 3 + kh) * 3 + kw], acc);
                    }
                }
            }
        }
    }
    dwout[(size_t)c * NPOS + pos] = acc;
}

// ---------------------------------------------------------------------------
// Kernel B: pointwise (64->32)+bias+ReLU, V projection (32->64) -> V[pos][64],
//           K score rows {0,32} * 1/sqrt(32) -> Ksc[2][NPOS]
// one thread per voxel
// ---------------------------------------------------------------------------
__global__ __launch_bounds__(256) void pwproj(
    const float* __restrict__ dwout,  // [64][NPOS]
    const float* __restrict__ pw_w,   // [32][64]
    const float* __restrict__ pw_b,   // [32]
    const float* __restrict__ k_w,    // [64][32]
    const float* __restrict__ v_w,    // [64][32]
    float* __restrict__ V,            // [NPOS][64]
    float* __restrict__ Ksc)          // [2][NPOS]
{
    const int pos = blockIdx.x * 256 + threadIdx.x;

    float f2[NC2];
    #pragma unroll
    for (int o = 0; o < NC2; ++o) f2[o] = pw_b[o];

    #pragma unroll 8
    for (int c = 0; c < NCH; ++c) {
        float x = dwout[(size_t)c * NPOS + pos];
        #pragma unroll
        for (int o = 0; o < NC2; ++o)
            f2[o] = fmaf(pw_w[o * NCH + c], x, f2[o]);
    }

    #pragma unroll
    for (int o = 0; o < NC2; ++o) f2[o] = fmaxf(f2[o], 0.0f);

    float4* vout = (float4*)(V + (size_t)pos * NCH);
    #pragma unroll
    for (int j4 = 0; j4 < NCH / 4; ++j4) {
        float4 r;
        float* rp = (float*)&r;
        #pragma unroll
        for (int q = 0; q < 4; ++q) {
            int j = j4 * 4 + q;
            float a = 0.0f;
            #pragma unroll
            for (int o = 0; o < NC2; ++o) a = fmaf(v_w[j * NC2 + o], f2[o], a);
            rp[q] = a;
        }
        vout[j4] = r;
    }

    const float scale = 0.17677669529663687f;
    #pragma unroll
    for (int h = 0; h < 2; ++h) {
        float a = 0.0f;
        #pragma unroll
        for (int o = 0; o < NC2; ++o) a = fmaf(k_w[(h * 32) * NC2 + o], f2[o], a);
        Ksc[h * NPOS + pos] = a * scale;
    }
}

// ---------------------------------------------------------------------------
// Fallback: original fully-fused front kernel (used only if ws too small)
// ---------------------------------------------------------------------------
__global__ __launch_bounds__(256) void fused_front(
    const float* __restrict__ feat, const float* __restrict__ dw_w,
    const float* __restrict__ dw_b, const float* __restrict__ pw_w,
    const float* __restrict__ pw_b, const float* __restrict__ k_w,
    const float* __restrict__ v_w, float* __restrict__ V, float* __restrict__ Ksc)
{
    const int pos = blockIdx.x * 256 + threadIdx.x;
    const int ow = pos % DP;
    const int oh = (pos / DP) % DP;
    const int od = pos / (DP * DP);

    float f2[NC2];
    #pragma unroll
    for (int o = 0; o < NC2; ++o) f2[o] = pw_b[o];

    #pragma unroll 1
    for (int c = 0; c < NCH; ++c) {
        float acc = dw_b[c];
        const float* fc = feat + (size_t)c * (DIN * DIN * DIN);
        const float* wc = dw_w + c * 27;
        #pragma unroll
        for (int kd = 0; kd < 3; ++kd) {
            int id = od * 2 - 1 + kd;
            if ((unsigned)id < (unsigned)DIN) {
                #pragma unroll
                for (int kh = 0; kh < 3; ++kh) {
                    int ih = oh * 2 - 1 + kh;
                    if ((unsigned)ih < (unsigned)DIN) {
                        const float* row = fc + ((size_t)id * DIN + ih) * DIN;
                        #pragma unroll
                        for (int kw = 0; kw < 3; ++kw) {
                            int iw = ow * 2 - 1 + kw;
                            if ((unsigned)iw < (unsigned)DIN)
                                acc = fmaf(row[iw], wc[(kd * 3 + kh) * 3 + kw], acc);
                        }
                    }
                }
            }
        }
        #pragma unroll
        for (int o = 0; o < NC2; ++o)
            f2[o] = fmaf(pw_w[o * NCH + c], acc, f2[o]);
    }
    #pragma unroll
    for (int o = 0; o < NC2; ++o) f2[o] = fmaxf(f2[o], 0.0f);

    float* vout = V + (size_t)pos * NCH;
    #pragma unroll 1
    for (int j = 0; j < NCH; ++j) {
        float a = 0.0f;
        #pragma unroll
        for (int o = 0; o < NC2; ++o) a = fmaf(v_w[j * NC2 + o], f2[o], a);
        vout[j] = a;
    }
    const float scale = 0.17677669529663687f;
    #pragma unroll
    for (int h = 0; h < 2; ++h) {
        float a = 0.0f;
        #pragma unroll
        for (int o = 0; o < NC2; ++o) a = fmaf(k_w[(h * 32) * NC2 + o], f2[o], a);
        Ksc[h * NPOS + pos] = a * scale;
    }
}

// ---------------------------------------------------------------------------
// Kernel 2: per-center windowed attention + output head (unchanged)
// ---------------------------------------------------------------------------
__global__ __launch_bounds__(256) void attn_out(
    const float* __restrict__ V,      // [NPOS][64]
    const float* __restrict__ Ksc,    // [2][NPOS]
    const float* __restrict__ out_w,  // [3][64]
    const float* __restrict__ out_b,  // [3]
    float* __restrict__ out)          // [3][NG]
{
    const int lo_t[12] = {0,1,5,9,14,18,22,26,31,35,39,44};
    const int hi_t[12] = {4,8,12,16,21,25,29,33,38,42,46,48};

    const int g   = blockIdx.x;
    const int tid = threadIdx.x;
    const int lane = tid & 63;
    const int wv   = tid >> 6;

    const int gz = g % 12, gy = (g / 12) % 12, gx = g / 144;
    const int lox = lo_t[gx], hix = hi_t[gx];
    const int loy = lo_t[gy], hiy = hi_t[gy];
    const int loz = lo_t[gz], hiz = hi_t[gz];

    __shared__ int   s_flat[WIN3];
    __shared__ float s_attn[2][WIN3];
    __shared__ float s_red[4];

    for (int w = tid; w < WIN3; w += 256) {
        int kd = w / 49, kh = (w / 7) % 7, kw = w % 7;
        int ix = lox + kd, iy = loy + kh, iz = loz + kw;
        bool m = (ix < hix) && (iy < hiy) && (iz < hiz);
        if (ix >= hix) ix = lox;
        if (iy >= hiy) iy = loy;
        if (iz >= hiz) iz = loz;
        int flat = (ix * DP + iy) * DP + iz;
        s_flat[w] = m ? flat : (flat | (int)0x80000000);
    }
    __syncthreads();

    const float NEG_INF = -__builtin_inff();
    float sums[2];

    #pragma unroll
    for (int h = 0; h < 2; ++h) {
        float sc0 = NEG_INF, sc1 = NEG_INF;
        {
            int fv = s_flat[tid];
            if (fv >= 0) sc0 = Ksc[h * NPOS + fv];
        }
        if (tid + 256 < WIN3) {
            int fv = s_flat[tid + 256];
            if (fv >= 0) sc1 = Ksc[h * NPOS + fv];
        }
        float lmax = fmaxf(sc0, sc1);
        #pragma unroll
        for (int off = 32; off; off >>= 1) lmax = fmaxf(lmax, __shfl_xor(lmax, off));
        if (lane == 0) s_red[wv] = lmax;
        __syncthreads();
        float gmax = fmaxf(fmaxf(s_red[0], s_red[1]), fmaxf(s_red[2], s_red[3]));
        __syncthreads();

        float lsum = 0.0f;
        {
            float e = (sc0 == NEG_INF) ? 0.0f : expf(sc0 - gmax);
            s_attn[h][tid] = e;
            lsum += e;
        }
        if (tid + 256 < WIN3) {
            float e = (sc1 == NEG_INF) ? 0.0f : expf(sc1 - gmax);
            s_attn[h][tid + 256] = e;
            lsum += e;
        }
        #pragma unroll
        for (int off = 32; off; off >>= 1) lsum += __shfl_xor(lsum, off);
        if (lane == 0) s_red[wv] = lsum;
        __syncthreads();
        sums[h] = s_red[0] + s_red[1] + s_red[2] + s_red[3];
        __syncthreads();
    }

    const int h = lane >> 5;
    float acc = 0.0f;
    for (int w = wv; w < WIN3; w += 4) {
        int fv = s_flat[w] & 0x7fffffff;
        float a = s_attn[h][w];
        acc = fmaf(a, V[(size_t)fv * NCH + lane], acc);
    }

    __shared__ float s_pctx[4][NCH];
    __shared__ float s_ctx[NCH];
    s_pctx[wv][lane] = acc;
    __syncthreads();
    if (wv == 0) {
        float ctx = s_pctx[0][lane] + s_pctx[1][lane] + s_pctx[2][lane] + s_pctx[3][lane];
        ctx /= sums[h];
        s_ctx[lane] = ctx;
    }
    __syncthreads();

    if (tid < 3) {
        float a = out_b[tid];
        #pragma unroll
        for (int j = 0; j < NCH; ++j) a = fmaf(out_w[tid * NCH + j], s_ctx[j], a);
        out[tid * NG + g] = a;
    }
}

// ---------------------------------------------------------------------------
extern "C" void kernel_launch(void* const* d_in, const int* in_sizes, int n_in,
                              void* d_out, int out_size, void* d_ws, size_t ws_size,
                              hipStream_t stream) {
    const float* feat  = (const float*)d_in[0];
    const float* dw_w  = (const float*)d_in[1];
    const float* dw_b  = (const float*)d_in[2];
    const float* pw_w  = (const float*)d_in[3];
    const float* pw_b  = (const float*)d_in[4];
    const float* k_w   = (const float*)d_in[5];
    const float* v_w   = (const float*)d_in[6];
    const float* out_w = (const float*)d_in[7];
    const float* out_b = (const float*)d_in[8];
    float* out = (float*)d_out;

    const size_t need = (size_t)(NCH + NCH + 2) * NPOS * sizeof(float); // ~57.5 MB

    if (ws_size >= need) {
        float* dwout = (float*)d_ws;                        // [64][NPOS]
        float* V     = dwout + (size_t)NCH * NPOS;          // [NPOS][64]
        float* Ksc   = V + (size_t)NPOS * NCH;              // [2][NPOS]

        hipLaunchKernelGGL(dwconv, dim3(NCH * (NPOS / 256)), dim3(256), 0, stream,
                           feat, dw_w, dw_b, dwout);
        hipLaunchKernelGGL(pwproj, dim3(NPOS / 256), dim3(256), 0, stream,
                           dwout, pw_w, pw_b, k_w, v_w, V, Ksc);
        hipLaunchKernelGGL(attn_out, dim3(NG), dim3(256), 0, stream,
                           V, Ksc, out_w, out_b, out);
    } else {
        float* V   = (float*)d_ws;
        float* Ksc = V + (size_t)NPOS * NCH;
        hipLaunchKernelGGL(fused_front, dim3(NPOS / 256), dim3(256), 0, stream,
                           feat, dw_w, dw_b, pw_w, pw_b, k_w, v_w, V, Ksc);
        hipLaunchKernelGGL(attn_out, dim3(NG), dim3(256), 0, stream,
                           V, Ksc, out_w, out_b, out);
    }
}

// Round 3
// 154.118 us; speedup vs baseline: 2.2978x; 1.4147x over previous
//
#include <hip/hip_runtime.h>

#define DIN 96
#define DP 48
#define NPOS (48*48*48)   // 110592
#define NG 1728           // 12^3
#define WIN3 343
#define NCH 64
#define NC2 32

// ---------------------------------------------------------------------------
// Kernel A: depthwise 3x3x3 stride-2 pad-1 conv + bias -> dwout[c][pos]
// Each thread computes a 2(d) x 1(h) x 2(w) output micro-tile.
// Input footprint: 5 planes x 3 rows, fetched as float4 + scalar per row
// -> 30 independent coalesced loads, 4 independent accumulators.
// ---------------------------------------------------------------------------
__global__ __launch_bounds__(256) void dwconv4(
    const float* __restrict__ feat,   // [64][96][96][96]
    const float* __restrict__ dw_w,   // [64][27]
    const float* __restrict__ dw_b,   // [64]
    float* __restrict__ dwout)        // [64][NPOS]
{
    const int c   = blockIdx.y;
    const int idx = blockIdx.x * 256 + threadIdx.x;   // 0..27647
    const int t   = idx % 24;                         // w-pair index (out w = 2t,2t+1)
    const int oh  = (idx / 24) % 48;
    const int odp = idx / (24 * 48);                  // d-pair index (out d = 2odp,2odp+1)

    const float* fc = feat + (size_t)c * (DIN * DIN * DIN);
    const float* wc = dw_w + c * 27;
    float w[27];
    #pragma unroll
    for (int i = 0; i < 27; ++i) w[i] = wc[i];        // wave-uniform -> SGPRs

    float a00 = 0.f, a01 = 0.f, a10 = 0.f, a11 = 0.f;

    #pragma unroll
    for (int dd = 0; dd < 5; ++dd) {
        const int id = 4 * odp - 1 + dd;              // input plane
        if (id >= 0) {
            #pragma unroll
            for (int kh = 0; kh < 3; ++kh) {
                const int ih = 2 * oh - 1 + kh;       // input row
                if (ih >= 0) {
                    const float* row = fc + ((size_t)id * DIN + ih) * DIN;
                    const float4 f4 = *(const float4*)(row + 4 * t);  // w: 4t..4t+3
                    const float  s  = (t > 0) ? row[4 * t - 1] : 0.0f; // w: 4t-1
                    if (dd <= 2) {  // contributes to out depth 2*odp with kd=dd
                        const float w0 = w[(dd * 3 + kh) * 3 + 0];
                        const float w1 = w[(dd * 3 + kh) * 3 + 1];
                        const float w2 = w[(dd * 3 + kh) * 3 + 2];
                        a00 = fmaf(s,    w0, fmaf(f4.x, w1, fmaf(f4.y, w2, a00)));
                        a01 = fmaf(f4.y, w0, fmaf(f4.z, w1, fmaf(f4.w, w2, a01)));
                    }
                    if (dd >= 2) {  // contributes to out depth 2*odp+1 with kd=dd-2
                        const int kd = dd - 2;
                        const float w0 = w[(kd * 3 + kh) * 3 + 0];
                        const float w1 = w[(kd * 3 + kh) * 3 + 1];
                        const float w2 = w[(kd * 3 + kh) * 3 + 2];
                        a10 = fmaf(s,    w0, fmaf(f4.x, w1, fmaf(f4.y, w2, a10)));
                        a11 = fmaf(f4.y, w0, fmaf(f4.z, w1, fmaf(f4.w, w2, a11)));
                    }
                }
            }
        }
    }

    const float b = dw_b[c];
    const int od0 = odp * 2;
    const size_t base = (size_t)c * NPOS + ((size_t)od0 * DP + oh) * DP + 2 * t;
    *(float2*)(dwout + base)              = make_float2(a00 + b, a01 + b);
    *(float2*)(dwout + base + DP * DP)    = make_float2(a10 + b, a11 + b);
}

// ---------------------------------------------------------------------------
// Kernel B: pointwise (64->32)+bias+ReLU, V projection (32->64) -> V[pos][64],
//           K score rows {0,32} * 1/sqrt(32) -> Ksc[2][NPOS]
// ---------------------------------------------------------------------------
__global__ __launch_bounds__(256) void pwproj(
    const float* __restrict__ dwout,  // [64][NPOS]
    const float* __restrict__ pw_w,   // [32][64]
    const float* __restrict__ pw_b,   // [32]
    const float* __restrict__ k_w,    // [64][32]
    const float* __restrict__ v_w,    // [64][32]
    float* __restrict__ V,            // [NPOS][64]
    float* __restrict__ Ksc)          // [2][NPOS]
{
    const int pos = blockIdx.x * 256 + threadIdx.x;

    float f2[NC2];
    #pragma unroll
    for (int o = 0; o < NC2; ++o) f2[o] = pw_b[o];

    #pragma unroll 8
    for (int c = 0; c < NCH; ++c) {
        float x = dwout[(size_t)c * NPOS + pos];
        #pragma unroll
        for (int o = 0; o < NC2; ++o)
            f2[o] = fmaf(pw_w[o * NCH + c], x, f2[o]);
    }

    #pragma unroll
    for (int o = 0; o < NC2; ++o) f2[o] = fmaxf(f2[o], 0.0f);

    float4* vout = (float4*)(V + (size_t)pos * NCH);
    #pragma unroll
    for (int j4 = 0; j4 < NCH / 4; ++j4) {
        float4 r;
        float* rp = (float*)&r;
        #pragma unroll
        for (int q = 0; q < 4; ++q) {
            int j = j4 * 4 + q;
            float a = 0.0f;
            #pragma unroll
            for (int o = 0; o < NC2; ++o) a = fmaf(v_w[j * NC2 + o], f2[o], a);
            rp[q] = a;
        }
        vout[j4] = r;
    }

    const float scale = 0.17677669529663687f;
    #pragma unroll
    for (int h = 0; h < 2; ++h) {
        float a = 0.0f;
        #pragma unroll
        for (int o = 0; o < NC2; ++o) a = fmaf(k_w[(h * 32) * NC2 + o], f2[o], a);
        Ksc[h * NPOS + pos] = a * scale;
    }
}

// ---------------------------------------------------------------------------
// Kernel 2: per-center windowed attention + output head
// ---------------------------------------------------------------------------
__global__ __launch_bounds__(256) void attn_out(
    const float* __restrict__ V,      // [NPOS][64]
    const float* __restrict__ Ksc,    // [2][NPOS]
    const float* __restrict__ out_w,  // [3][64]
    const float* __restrict__ out_b,  // [3]
    float* __restrict__ out)          // [3][NG]
{
    const int lo_t[12] = {0,1,5,9,14,18,22,26,31,35,39,44};
    const int hi_t[12] = {4,8,12,16,21,25,29,33,38,42,46,48};

    const int g   = blockIdx.x;
    const int tid = threadIdx.x;
    const int lane = tid & 63;
    const int wv   = tid >> 6;

    const int gz = g % 12, gy = (g / 12) % 12, gx = g / 144;
    const int lox = lo_t[gx], hix = hi_t[gx];
    const int loy = lo_t[gy], hiy = hi_t[gy];
    const int loz = lo_t[gz], hiz = hi_t[gz];

    __shared__ int   s_flat[WIN3];
    __shared__ float s_attn[2][WIN3];
    __shared__ float s_red[4];

    for (int w = tid; w < WIN3; w += 256) {
        int kd = w / 49, kh = (w / 7) % 7, kw = w % 7;
        int ix = lox + kd, iy = loy + kh, iz = loz + kw;
        bool m = (ix < hix) && (iy < hiy) && (iz < hiz);
        if (ix >= hix) ix = lox;
        if (iy >= hiy) iy = loy;
        if (iz >= hiz) iz = loz;
        int flat = (ix * DP + iy) * DP + iz;
        s_flat[w] = m ? flat : (flat | (int)0x80000000);
    }
    __syncthreads();

    const float NEG_INF = -__builtin_inff();
    float sums[2];

    #pragma unroll
    for (int h = 0; h < 2; ++h) {
        float sc0 = NEG_INF, sc1 = NEG_INF;
        {
            int fv = s_flat[tid];
            if (fv >= 0) sc0 = Ksc[h * NPOS + fv];
        }
        if (tid + 256 < WIN3) {
            int fv = s_flat[tid + 256];
            if (fv >= 0) sc1 = Ksc[h * NPOS + fv];
        }
        float lmax = fmaxf(sc0, sc1);
        #pragma unroll
        for (int off = 32; off; off >>= 1) lmax = fmaxf(lmax, __shfl_xor(lmax, off));
        if (lane == 0) s_red[wv] = lmax;
        __syncthreads();
        float gmax = fmaxf(fmaxf(s_red[0], s_red[1]), fmaxf(s_red[2], s_red[3]));
        __syncthreads();

        float lsum = 0.0f;
        {
            float e = (sc0 == NEG_INF) ? 0.0f : expf(sc0 - gmax);
            s_attn[h][tid] = e;
            lsum += e;
        }
        if (tid + 256 < WIN3) {
            float e = (sc1 == NEG_INF) ? 0.0f : expf(sc1 - gmax);
            s_attn[h][tid + 256] = e;
            lsum += e;
        }
        #pragma unroll
        for (int off = 32; off; off >>= 1) lsum += __shfl_xor(lsum, off);
        if (lane == 0) s_red[wv] = lsum;
        __syncthreads();
        sums[h] = s_red[0] + s_red[1] + s_red[2] + s_red[3];
        __syncthreads();
    }

    const int h = lane >> 5;
    float acc = 0.0f;
    for (int w = wv; w < WIN3; w += 4) {
        int fv = s_flat[w] & 0x7fffffff;
        float a = s_attn[h][w];
        acc = fmaf(a, V[(size_t)fv * NCH + lane], acc);
    }

    __shared__ float s_pctx[4][NCH];
    __shared__ float s_ctx[NCH];
    s_pctx[wv][lane] = acc;
    __syncthreads();
    if (wv == 0) {
        float ctx = s_pctx[0][lane] + s_pctx[1][lane] + s_pctx[2][lane] + s_pctx[3][lane];
        ctx /= sums[h];
        s_ctx[lane] = ctx;
    }
    __syncthreads();

    if (tid < 3) {
        float a = out_b[tid];
        #pragma unroll
        for (int j = 0; j < NCH; ++j) a = fmaf(out_w[tid * NCH + j], s_ctx[j], a);
        out[tid * NG + g] = a;
    }
}

// ---------------------------------------------------------------------------
extern "C" void kernel_launch(void* const* d_in, const int* in_sizes, int n_in,
                              void* d_out, int out_size, void* d_ws, size_t ws_size,
                              hipStream_t stream) {
    const float* feat  = (const float*)d_in[0];
    const float* dw_w  = (const float*)d_in[1];
    const float* dw_b  = (const float*)d_in[2];
    const float* pw_w  = (const float*)d_in[3];
    const float* pw_b  = (const float*)d_in[4];
    const float* k_w   = (const float*)d_in[5];
    const float* v_w   = (const float*)d_in[6];
    const float* out_w = (const float*)d_in[7];
    const float* out_b = (const float*)d_in[8];
    float* out = (float*)d_out;

    float* dwout = (float*)d_ws;                        // [64][NPOS]
    float* V     = dwout + (size_t)NCH * NPOS;          // [NPOS][64]
    float* Ksc   = V + (size_t)NPOS * NCH;              // [2][NPOS]

    // dwconv4: 27648 threads/channel = 108 blocks of 256; grid (108, 64)
    hipLaunchKernelGGL(dwconv4, dim3(108, NCH), dim3(256), 0, stream,
                       feat, dw_w, dw_b, dwout);
    hipLaunchKernelGGL(pwproj, dim3(NPOS / 256), dim3(256), 0, stream,
                       dwout, pw_w, pw_b, k_w, v_w, V, Ksc);
    hipLaunchKernelGGL(attn_out, dim3(NG), dim3(256), 0, stream,
                       V, Ksc, out_w, out_b, out);
}